// Round 1
// baseline (800.689 us; speedup 1.0000x reference)
//
#include <hip/hip_runtime.h>

#define RES 512
#define FEAT 32
#define NPLANES 6

// ---------------------------------------------------------------------------
// Transpose planes [p][c][y][x] -> [p][y][x][c] so that all 32 channels at a
// given (y,x) are contiguous (128 B). Each block: one (plane, row, 64-wide x
// tile). Reads coalesced along x, writes coalesced along (x,c) (the whole
// 64x32 tile is 8 KB contiguous in the output).
// ---------------------------------------------------------------------------
__global__ __launch_bounds__(256) void transpose_kernel(
    const float* __restrict__ in, float* __restrict__ out)
{
    __shared__ float tile[FEAT][65];   // +1 pad: bank-conflict-free both phases
    const int b = blockIdx.x;
    const int xt = b & 7;              // 8 tiles of 64 along x
    const int y  = (b >> 3) & (RES - 1);
    const int p  = b >> 12;            // 512*8 = 4096 = 2^12 blocks per plane
    const int xbase = xt << 6;

    const size_t pb = (size_t)p * (FEAT * RES * RES) + (size_t)y * RES + xbase;
    // Load 32 x 64 tile: 512 float4 loads, 2 per thread, coalesced along x.
    #pragma unroll
    for (int j = 0; j < 2; ++j) {
        const int f  = threadIdx.x + j * 256;   // float4 index 0..511
        const int c  = f >> 4;                  // 16 float4 per row of 64
        const int x4 = (f & 15) << 2;
        const float4 v = *(const float4*)(in + pb + (size_t)c * (RES * RES) + x4);
        tile[c][x4 + 0] = v.x;
        tile[c][x4 + 1] = v.y;
        tile[c][x4 + 2] = v.z;
        tile[c][x4 + 3] = v.w;
    }
    __syncthreads();

    // Write: output tile is 2048 contiguous floats at ob; element k maps to
    // x = k>>5, c = k&31.
    const size_t ob = (((size_t)p * RES + y) * RES + xbase) * FEAT;
    #pragma unroll
    for (int j = 0; j < 2; ++j) {
        const int k = (threadIdx.x + j * 256) << 2;  // 0..2044 step 4
        float4 v;
        v.x = tile[(k + 0) & 31][(k + 0) >> 5];
        v.y = tile[(k + 1) & 31][(k + 1) >> 5];
        v.z = tile[(k + 2) & 31][(k + 2) >> 5];
        v.w = tile[(k + 3) & 31][(k + 3) >> 5];
        *(float4*)(out + ob + k) = v;
    }
}

// ---------------------------------------------------------------------------
// Sampling kernel. One thread per (point, channel). 32 lanes share a point,
// so each bilinear tap is a 128 B coalesced read (TRANSPOSED layout).
// ---------------------------------------------------------------------------
template <bool TRANSPOSED>
__global__ __launch_bounds__(256) void sample_kernel(
    const float* __restrict__ pts, const float* __restrict__ tm,
    const float* __restrict__ planes, float* __restrict__ out, int npts)
{
    const int t  = blockIdx.x * 256 + threadIdx.x;
    const int pt = t >> 5;
    const int c  = t & 31;
    if (pt >= npts) return;

    const float px = pts[(size_t)pt * 3 + 0];
    const float py = pts[(size_t)pt * 3 + 1];
    const float pz = pts[(size_t)pt * 3 + 2];
    const float tv = tm[pt];

    // Match reference fp32 op order: (p - (-1.6)) / 3.2 * 2 - 1
    float d[4];
    d[0] = (px + 1.6f) / 3.2f * 2.0f - 1.0f;
    d[1] = (py + 1.6f) / 3.2f * 2.0f - 1.0f;
    d[2] = (pz + 1.6f) / 3.2f * 2.0f - 1.0f;
    d[3] = tv * 2.0f - 1.0f;

    // (x-coord index, y-coord index) per plane, from idx table
    const int xi[NPLANES] = {0, 0, 3, 1, 3, 3};
    const int yi[NPLANES] = {1, 2, 0, 2, 1, 2};

    float f[NPLANES];
    #pragma unroll
    for (int q = 0; q < NPLANES; ++q) {
        const float u = d[xi[q]];
        const float v = d[yi[q]];
        float fx = (u + 1.0f) * 0.5f * 511.0f;
        float fy = (v + 1.0f) * 0.5f * 511.0f;
        fx = fminf(fmaxf(fx, 0.0f), 511.0f);
        fy = fminf(fmaxf(fy, 0.0f), 511.0f);
        const float x0f = floorf(fx);
        const float y0f = floorf(fy);
        const float wx = fx - x0f;
        const float wy = fy - y0f;
        const int x0 = (int)x0f;
        const int y0 = (int)y0f;
        const int x1 = min(x0 + 1, RES - 1);
        const int y1 = min(y0 + 1, RES - 1);

        float v00, v01, v10, v11;
        if (TRANSPOSED) {
            // [p][y][x][c]
            const float* P = planes + ((size_t)q << 23);  // q * 512*512*32
            const int r0 = y0 << 9, r1 = y1 << 9;
            v00 = P[((size_t)(r0 + x0) << 5) + c];
            v01 = P[((size_t)(r0 + x1) << 5) + c];
            v10 = P[((size_t)(r1 + x0) << 5) + c];
            v11 = P[((size_t)(r1 + x1) << 5) + c];
        } else {
            // [p][c][y][x]  (fallback, uncoalesced but correct)
            const float* P = planes + ((size_t)(q * FEAT + c) << 18);
            const int r0 = y0 << 9, r1 = y1 << 9;
            v00 = P[r0 + x0];
            v01 = P[r0 + x1];
            v10 = P[r1 + x0];
            v11 = P[r1 + x1];
        }
        f[q] = v00 * ((1.0f - wx) * (1.0f - wy)) + v01 * (wx * (1.0f - wy)) +
               v10 * ((1.0f - wx) * wy)          + v11 * (wx * wy);
    }

    const float space     = f[0] * f[1] * f[3];
    const float spacetime = f[2] * f[4] * f[5];
    out[(size_t)pt * FEAT + c] = space;
    out[(size_t)npts * FEAT + (size_t)pt * FEAT + c] = spacetime;
}

extern "C" void kernel_launch(void* const* d_in, const int* in_sizes, int n_in,
                              void* d_out, int out_size, void* d_ws, size_t ws_size,
                              hipStream_t stream) {
    const float* pts    = (const float*)d_in[0];
    const float* tm     = (const float*)d_in[1];
    const float* planes = (const float*)d_in[2];
    float* out = (float*)d_out;
    const int npts = in_sizes[0] / 3;

    const size_t need = (size_t)NPLANES * FEAT * RES * RES * sizeof(float);
    const int total = npts * FEAT;
    const int blocks = (total + 255) / 256;

    if (ws_size >= need) {
        float* T = (float*)d_ws;
        transpose_kernel<<<NPLANES * RES * 8, 256, 0, stream>>>(planes, T);
        sample_kernel<true><<<blocks, 256, 0, stream>>>(pts, tm, T, out, npts);
    } else {
        sample_kernel<false><<<blocks, 256, 0, stream>>>(pts, tm, planes, out, npts);
    }
}

// Round 2
// 712.933 us; speedup vs baseline: 1.1231x; 1.1231x over previous
//
#include <hip/hip_runtime.h>
#include <hip/hip_fp16.h>

#define RES 512
#define FEAT 32
#define NPLANES 6
#define XT 128
#define TP (XT + 4)   // LDS tile pitch (floats): 132 -> 528 B rows (16B-aligned), bank shift 4/row

// ---------------------------------------------------------------------------
// Transpose + downconvert: [p][c][y][x] fp32 -> [p][y][x][c] fp16.
// Block = (plane, row, 128-wide x tile). Reads 512 B runs per channel,
// writes 8 KB contiguous fp16 per block.
// Bank math (pitch 132 => bank = (4c + x) & 31): phase-1 b128 writes hit each
// bank uniformly (8 words/bank = minimum); phase-2 scalar reads are 2-way
// aliased (lanes 2m / 2m+1) which is free on gfx950 (m136).
// ---------------------------------------------------------------------------
__global__ __launch_bounds__(256) void transpose_fp16_kernel(
    const float* __restrict__ in, __half* __restrict__ out)
{
    __shared__ float tile[FEAT][TP];
    const int b  = blockIdx.x;
    const int xt = b & 3;              // 4 tiles of 128 along x
    const int y  = (b >> 2) & (RES - 1);
    const int p  = b >> 11;            // 512*4 = 2048 blocks per plane
    const int xbase = xt << 7;

    const size_t pb = (size_t)p * ((size_t)FEAT * RES * RES) + (size_t)y * RES + xbase;
    #pragma unroll
    for (int j = 0; j < 4; ++j) {
        const int f  = threadIdx.x + j * 256;   // float4 index 0..1023
        const int c  = f >> 5;                  // 32 float4 per 128-wide row
        const int x4 = (f & 31) << 2;
        const float4 v = *(const float4*)(in + pb + (size_t)c * (RES * RES) + x4);
        *(float4*)&tile[c][x4] = v;
    }
    __syncthreads();

    // Output element k (0..4095): x = k>>5, c = k&31. Thread t covers
    // k = 16t..16t+15  =>  column m = t>>1, channels c0..c0+15, c0 = (t&1)*16.
    const int m  = threadIdx.x >> 1;
    const int c0 = (threadIdx.x & 1) << 4;
    union { __half h[16]; float4 f4[2]; } u;
    #pragma unroll
    for (int j = 0; j < 16; ++j)
        u.h[j] = __float2half_rn(tile[c0 + j][m]);

    const size_t ob = (((size_t)p * RES + y) * RES + xbase) * FEAT
                    + (size_t)threadIdx.x * 16;
    *(float4*)(out + ob)     = u.f4[0];
    *(float4*)(out + ob + 8) = u.f4[1];
}

// ---------------------------------------------------------------------------
// Sampler: 4 threads per point, 8 channels per thread. Each tap is a 16 B
// load (8 halves); 4 lanes of a point form a 64 B contiguous segment.
// ---------------------------------------------------------------------------
__device__ __forceinline__ void unpack8(const float4 r, float* o)
{
    const __half2* h = (const __half2*)&r;
    float2 p;
    p = __half22float2(h[0]); o[0] = p.x; o[1] = p.y;
    p = __half22float2(h[1]); o[2] = p.x; o[3] = p.y;
    p = __half22float2(h[2]); o[4] = p.x; o[5] = p.y;
    p = __half22float2(h[3]); o[6] = p.x; o[7] = p.y;
}

template <int XIq, int YIq, int Q>
__device__ __forceinline__ void sample_plane(
    const float* d, const __half* __restrict__ planes, int sub, float* f)
{
    const float u = d[XIq];
    const float v = d[YIq];
    float fx = fminf(fmaxf((u + 1.0f) * 0.5f * 511.0f, 0.0f), 511.0f);
    float fy = fminf(fmaxf((v + 1.0f) * 0.5f * 511.0f, 0.0f), 511.0f);
    const float x0f = floorf(fx), y0f = floorf(fy);
    const float wx = fx - x0f,   wy = fy - y0f;
    const int x0 = (int)x0f, y0 = (int)y0f;
    const int x1 = min(x0 + 1, RES - 1), y1 = min(y0 + 1, RES - 1);
    const float w00 = (1.0f - wx) * (1.0f - wy);
    const float w01 = wx * (1.0f - wy);
    const float w10 = (1.0f - wx) * wy;
    const float w11 = wx * wy;

    const __half* P = planes + ((size_t)Q << 23) + (sub << 3);  // plane + channel-group base
    const int r0 = y0 << 9, r1 = y1 << 9;
    const float4 a00 = *(const float4*)(P + ((size_t)(r0 + x0) << 5));
    const float4 a01 = *(const float4*)(P + ((size_t)(r0 + x1) << 5));
    const float4 a10 = *(const float4*)(P + ((size_t)(r1 + x0) << 5));
    const float4 a11 = *(const float4*)(P + ((size_t)(r1 + x1) << 5));

    float v00[8], v01[8], v10[8], v11[8];
    unpack8(a00, v00); unpack8(a01, v01); unpack8(a10, v10); unpack8(a11, v11);
    #pragma unroll
    for (int i = 0; i < 8; ++i)
        f[i] = v00[i] * w00 + v01[i] * w01 + v10[i] * w10 + v11[i] * w11;
}

__global__ __launch_bounds__(256) void sample_fp16_kernel(
    const float* __restrict__ pts, const float* __restrict__ tm,
    const __half* __restrict__ planes, float* __restrict__ out, int npts)
{
    const int t  = blockIdx.x * 256 + threadIdx.x;
    const int pt = t >> 2;
    const int sub = t & 3;
    if (pt >= npts) return;

    float d[4];
    d[0] = (pts[(size_t)pt * 3 + 0] + 1.6f) / 3.2f * 2.0f - 1.0f;
    d[1] = (pts[(size_t)pt * 3 + 1] + 1.6f) / 3.2f * 2.0f - 1.0f;
    d[2] = (pts[(size_t)pt * 3 + 2] + 1.6f) / 3.2f * 2.0f - 1.0f;
    d[3] = tm[pt] * 2.0f - 1.0f;

    float f[8], sp[8], st[8];

    // space = (f0 * f1) * f3   (planes 0:(x,y)=(d0,d1), 1:(d0,d2), 3:(d1,d2))
    sample_plane<0, 1, 0>(d, planes, sub, sp);
    sample_plane<0, 2, 1>(d, planes, sub, f);
    #pragma unroll
    for (int i = 0; i < 8; ++i) sp[i] *= f[i];
    sample_plane<1, 2, 3>(d, planes, sub, f);
    #pragma unroll
    for (int i = 0; i < 8; ++i) sp[i] *= f[i];
    {
        float4* o = (float4*)(out + (size_t)pt * FEAT + (sub << 3));
        o[0] = *(float4*)&sp[0];
        o[1] = *(float4*)&sp[4];
    }

    // spacetime = (f2 * f4) * f5  (planes 2:(d3,d0), 4:(d3,d1), 5:(d3,d2))
    sample_plane<3, 0, 2>(d, planes, sub, st);
    sample_plane<3, 1, 4>(d, planes, sub, f);
    #pragma unroll
    for (int i = 0; i < 8; ++i) st[i] *= f[i];
    sample_plane<3, 2, 5>(d, planes, sub, f);
    #pragma unroll
    for (int i = 0; i < 8; ++i) st[i] *= f[i];
    {
        float4* o = (float4*)(out + (size_t)npts * FEAT + (size_t)pt * FEAT + (sub << 3));
        o[0] = *(float4*)&st[0];
        o[1] = *(float4*)&st[4];
    }
}

// ---------------------------------------------------------------------------
// Fallback (ws too small): sample original [p][c][y][x] fp32 layout directly.
// ---------------------------------------------------------------------------
__global__ __launch_bounds__(256) void sample_fallback_kernel(
    const float* __restrict__ pts, const float* __restrict__ tm,
    const float* __restrict__ planes, float* __restrict__ out, int npts)
{
    const int t  = blockIdx.x * 256 + threadIdx.x;
    const int pt = t >> 5;
    const int c  = t & 31;
    if (pt >= npts) return;

    float d[4];
    d[0] = (pts[(size_t)pt * 3 + 0] + 1.6f) / 3.2f * 2.0f - 1.0f;
    d[1] = (pts[(size_t)pt * 3 + 1] + 1.6f) / 3.2f * 2.0f - 1.0f;
    d[2] = (pts[(size_t)pt * 3 + 2] + 1.6f) / 3.2f * 2.0f - 1.0f;
    d[3] = tm[pt] * 2.0f - 1.0f;

    const int xi[NPLANES] = {0, 0, 3, 1, 3, 3};
    const int yi[NPLANES] = {1, 2, 0, 2, 1, 2};
    float f[NPLANES];
    #pragma unroll
    for (int q = 0; q < NPLANES; ++q) {
        const float u = d[xi[q]], v = d[yi[q]];
        float fx = fminf(fmaxf((u + 1.0f) * 0.5f * 511.0f, 0.0f), 511.0f);
        float fy = fminf(fmaxf((v + 1.0f) * 0.5f * 511.0f, 0.0f), 511.0f);
        const float x0f = floorf(fx), y0f = floorf(fy);
        const float wx = fx - x0f, wy = fy - y0f;
        const int x0 = (int)x0f, y0 = (int)y0f;
        const int x1 = min(x0 + 1, RES - 1), y1 = min(y0 + 1, RES - 1);
        const float* P = planes + ((size_t)(q * FEAT + c) << 18);
        const int r0 = y0 << 9, r1 = y1 << 9;
        f[q] = P[r0 + x0] * ((1.0f - wx) * (1.0f - wy)) + P[r0 + x1] * (wx * (1.0f - wy)) +
               P[r1 + x0] * ((1.0f - wx) * wy)          + P[r1 + x1] * (wx * wy);
    }
    out[(size_t)pt * FEAT + c] = f[0] * f[1] * f[3];
    out[(size_t)npts * FEAT + (size_t)pt * FEAT + c] = f[2] * f[4] * f[5];
}

extern "C" void kernel_launch(void* const* d_in, const int* in_sizes, int n_in,
                              void* d_out, int out_size, void* d_ws, size_t ws_size,
                              hipStream_t stream) {
    const float* pts    = (const float*)d_in[0];
    const float* tm     = (const float*)d_in[1];
    const float* planes = (const float*)d_in[2];
    float* out = (float*)d_out;
    const int npts = in_sizes[0] / 3;

    const size_t need = (size_t)NPLANES * FEAT * RES * RES * sizeof(__half);  // 96 MiB
    if (ws_size >= need) {
        __half* T = (__half*)d_ws;
        transpose_fp16_kernel<<<NPLANES * RES * 4, 256, 0, stream>>>(planes, T);
        const int blocks = (npts * 4 + 255) / 256;
        sample_fp16_kernel<<<blocks, 256, 0, stream>>>(pts, tm, T, out, npts);
    } else {
        const int blocks = (npts * 32 + 255) / 256;
        sample_fallback_kernel<<<blocks, 256, 0, stream>>>(pts, tm, planes, out, npts);
    }
}